// Round 1
// baseline (223.742 us; speedup 1.0000x reference)
//
#include <hip/hip_runtime.h>

// Problem constants
#define N_SAMP 32          // batch rows after flatten
#define D_FEAT 32768       // 128*16*16 pooled features
#define TVAL 100.0f

// ---------------------------------------------------------------------------
// Kernel 1: AvgPool2d(4,4) on (32,128,64,64) -> [32, 32768] row-major.
// One thread per pooled output element; float4 row loads (memory-bound pass).
// ---------------------------------------------------------------------------
__global__ __launch_bounds__(256) void pool_kernel(const float* __restrict__ xa,
                                                   const float* __restrict__ xb,
                                                   float* __restrict__ fa,
                                                   float* __restrict__ fb) {
    const float* in = blockIdx.y ? xb : xa;
    float* out = blockIdx.y ? fb : fa;
    int o = blockIdx.x * 256 + threadIdx.x;   // 0 .. 1048575
    int b  = o >> 15;
    int r  = o & 32767;
    int c  = r >> 8;
    int hp = (r >> 4) & 15;
    int wp = r & 15;
    // input[b][c][hp*4+row][wp*4 .. wp*4+3]
    const float* p = in + (size_t)(b * 128 + c) * 4096 + hp * 256 + wp * 4;
    float s = 0.f;
#pragma unroll
    for (int row = 0; row < 4; ++row) {
        float4 v = *(const float4*)(p + row * 64);
        s += v.x + v.y + v.z + v.w;
    }
    out[o] = s * 0.0625f;
}

// ---------------------------------------------------------------------------
// sinc-style kernel term: d==0 -> T else sin(d*T)/d  (matches jnp.where exactly:
// select is bitwise, so the NaN from __fdividef(0,0) never propagates)
// ---------------------------------------------------------------------------
__device__ __forceinline__ float kf(float a, float b) {
    float d = a - b;
    float s = __sinf(d * TVAL);
    float q = __fdividef(s, d);
    return (d == 0.0f) ? TVAL : q;
}

// ---------------------------------------------------------------------------
// Kernel 2: blocked MMD sums. Grid = 1536 blocks:
//   blk bits: [term(2) | ti(3) | tj(3) | chunk(3)]
//   term 0: (fa,fa)  term 1: (fb,fb)  term 2: (fa,fb)
// Each block: 4x4 pair tile over a 4096-float D-chunk.
// Reads 8 rows x 16KB = 128KB (L2/L3 resident) for 65536 sinc evals.
// Writes 16 deterministic partial sums (no atomics).
// ---------------------------------------------------------------------------
__global__ __launch_bounds__(256) void mmd_kernel(const float* __restrict__ fa,
                                                  const float* __restrict__ fb,
                                                  float* __restrict__ partials) {
    int blk   = blockIdx.x;
    int chunk = blk & 7;
    int tj    = (blk >> 3) & 7;
    int ti    = (blk >> 6) & 7;
    int term  = blk >> 9;
    const float* A = (term == 1) ? fb : fa;
    const float* B = (term == 0) ? fa : fb;
    const float* pa = A + (size_t)(ti * 4) * D_FEAT;
    const float* pb = B + (size_t)(tj * 4) * D_FEAT;
    int f0 = chunk * 4096 + threadIdx.x * 4;

    float acc[16];
#pragma unroll
    for (int k = 0; k < 16; ++k) acc[k] = 0.f;

#pragma unroll
    for (int it = 0; it < 4; ++it) {
        int f = f0 + it * 1024;
        float4 av[4], bv[4];
#pragma unroll
        for (int ii = 0; ii < 4; ++ii) av[ii] = *(const float4*)(pa + (size_t)ii * D_FEAT + f);
#pragma unroll
        for (int jj = 0; jj < 4; ++jj) bv[jj] = *(const float4*)(pb + (size_t)jj * D_FEAT + f);
#pragma unroll
        for (int ii = 0; ii < 4; ++ii) {
#pragma unroll
            for (int jj = 0; jj < 4; ++jj) {
                acc[ii * 4 + jj] += kf(av[ii].x, bv[jj].x) + kf(av[ii].y, bv[jj].y)
                                  + kf(av[ii].z, bv[jj].z) + kf(av[ii].w, bv[jj].w);
            }
        }
    }

    // block reduction: wave64 butterfly, then cross-wave via LDS
    __shared__ float red[4][16];
    int lane = threadIdx.x & 63;
    int wave = threadIdx.x >> 6;
#pragma unroll
    for (int k = 0; k < 16; ++k) {
        float v = acc[k];
#pragma unroll
        for (int m = 1; m < 64; m <<= 1) v += __shfl_xor(v, m, 64);
        if (lane == 0) red[wave][k] = v;
    }
    __syncthreads();
    if (threadIdx.x < 16) {
        float s = red[0][threadIdx.x] + red[1][threadIdx.x]
                + red[2][threadIdx.x] + red[3][threadIdx.x];
        partials[(size_t)blk * 16 + threadIdx.x] = s;
    }
}

// ---------------------------------------------------------------------------
// Kernel 3: finalize. 1536*16 = 24576 partials; weight +1 for xx/yy, -2 for xy.
// term = (p>>4) >> 9 = p >> 13. Double accumulation, divide by 32*32*32768.
// ---------------------------------------------------------------------------
__global__ __launch_bounds__(256) void fin_kernel(const float* __restrict__ partials,
                                                  float* __restrict__ out) {
    double s = 0.0;
    for (int p = threadIdx.x; p < 1536 * 16; p += 256) {
        double w = ((p >> 13) == 2) ? -2.0 : 1.0;
        s += w * (double)partials[p];
    }
    __shared__ double sh[256];
    sh[threadIdx.x] = s;
    __syncthreads();
    for (int m = 128; m > 0; m >>= 1) {
        if (threadIdx.x < m) sh[threadIdx.x] += sh[threadIdx.x + m];
        __syncthreads();
    }
    if (threadIdx.x == 0) out[0] = (float)(sh[0] / 33554432.0);
}

extern "C" void kernel_launch(void* const* d_in, const int* in_sizes, int n_in,
                              void* d_out, int out_size, void* d_ws, size_t ws_size,
                              hipStream_t stream) {
    const float* xa = (const float*)d_in[0];
    const float* xb = (const float*)d_in[1];
    float* fa = (float*)d_ws;                 // 1048576 floats
    float* fb = fa + (size_t)N_SAMP * D_FEAT; // 1048576 floats
    float* partials = fb + (size_t)N_SAMP * D_FEAT; // 24576 floats
    float* out = (float*)d_out;

    dim3 pg(4096, 2);
    pool_kernel<<<pg, 256, 0, stream>>>(xa, xb, fa, fb);
    mmd_kernel<<<1536, 256, 0, stream>>>(fa, fb, partials);
    fin_kernel<<<1, 256, 0, stream>>>(partials, out);
}

// Round 2
// 168.426 us; speedup vs baseline: 1.3284x; 1.3284x over previous
//
#include <hip/hip_runtime.h>

#define N_SAMP 32
#define D_FEAT 32768
#define TVAL 100.0f
#define SIN_C 15.91549430918953f   // 100 / (2*pi): v_sin_f32 takes revolutions
#define CHUNKS 32
#define CHUNK_F 1024               // D_FEAT / CHUNKS
#define NJOBS 136                  // 36 xx + 36 yy + 64 xy
#define NBLK (NJOBS * CHUNKS)      // 4352 = 17 * 256 CUs

// ---------------------------------------------------------------------------
// Kernel 1: AvgPool2d(4,4) on (32,128,64,64) -> [32, 32768] row-major.
// Memory-bound: 134 MB read. Each 16-lane group loads a contiguous 256B run.
// ---------------------------------------------------------------------------
__global__ __launch_bounds__(256) void pool_kernel(const float* __restrict__ xa,
                                                   const float* __restrict__ xb,
                                                   float* __restrict__ fa,
                                                   float* __restrict__ fb) {
    const float* in = blockIdx.y ? xb : xa;
    float* out = blockIdx.y ? fb : fa;
    int o = blockIdx.x * 256 + threadIdx.x;
    int b  = o >> 15;
    int r  = o & 32767;
    int c  = r >> 8;
    int hp = (r >> 4) & 15;
    int wp = r & 15;
    const float* p = in + (size_t)(b * 128 + c) * 4096 + hp * 256 + wp * 4;
    float s = 0.f;
#pragma unroll
    for (int row = 0; row < 4; ++row) {
        float4 v = *(const float4*)(p + row * 64);
        s += v.x + v.y + v.z + v.w;
    }
    out[o] = s * 0.0625f;
}

// sinc term: d==0 -> T else sin(d*T)/d. v_cndmask is a bitwise select, so the
// NaN from 0*inf on the d==0 lane never propagates. d==0 off-diagonal IS
// possible (~float collisions at 71M pairs), so the select must stay.
__device__ __forceinline__ float kf(float a, float b) {
    float d = a - b;
    float s = __builtin_amdgcn_sinf(d * SIN_C);   // == sin(d*100)
    float q = s * __builtin_amdgcn_rcpf(d);
    return (d == 0.0f) ? TVAL : q;
}

// ---------------------------------------------------------------------------
// Kernel 2: MMD partial sums, symmetry-reduced.
//   job < 36        : xx upper-tri tile (ti<=tj), weight = (ti==tj) ? 1 : 2
//   36 <= job < 72  : yy likewise
//   job >= 72       : xy full 8x8 tiles, weight = -2
// blk = job*CHUNKS + chunk; each block: 4x4 row-pair tile over 1024 floats.
// One weighted scalar partial per block (all 16 pairs share the weight).
// ---------------------------------------------------------------------------
__global__ __launch_bounds__(256) void mmd_kernel(const float* __restrict__ fa,
                                                  const float* __restrict__ fb,
                                                  float* __restrict__ partials) {
    int blk   = blockIdx.x;
    int chunk = blk & (CHUNKS - 1);
    int job   = blk >> 5;

    const float* A;
    const float* B;
    float w;
    if (job < 72) {
        int q = (job >= 36) ? job - 36 : job;
        const float* base = (job >= 36) ? fb : fa;
        int ti = 0, u = q;                 // unrank upper-tri incl diag (uniform scalar loop)
        while (u >= 8 - ti) { u -= 8 - ti; ++ti; }
        int tj = ti + u;
        A = base + (size_t)(ti * 4) * D_FEAT;
        B = base + (size_t)(tj * 4) * D_FEAT;
        w = (ti == tj) ? 1.0f : 2.0f;
    } else {
        int q = job - 72;
        A = fa + (size_t)((q >> 3) * 4) * D_FEAT;
        B = fb + (size_t)((q & 7) * 4) * D_FEAT;
        w = -2.0f;
    }

    int f = chunk * CHUNK_F + threadIdx.x * 4;
    float4 av[4], bv[4];
#pragma unroll
    for (int ii = 0; ii < 4; ++ii) av[ii] = *(const float4*)(A + (size_t)ii * D_FEAT + f);
#pragma unroll
    for (int jj = 0; jj < 4; ++jj) bv[jj] = *(const float4*)(B + (size_t)jj * D_FEAT + f);

    float acc[4] = {0.f, 0.f, 0.f, 0.f};   // split by jj for ILP on the trans pipe
#pragma unroll
    for (int ii = 0; ii < 4; ++ii) {
#pragma unroll
        for (int jj = 0; jj < 4; ++jj) {
            acc[jj] += kf(av[ii].x, bv[jj].x) + kf(av[ii].y, bv[jj].y)
                     + kf(av[ii].z, bv[jj].z) + kf(av[ii].w, bv[jj].w);
        }
    }
    float v = ((acc[0] + acc[1]) + (acc[2] + acc[3])) * w;

#pragma unroll
    for (int m = 1; m < 64; m <<= 1) v += __shfl_xor(v, m, 64);

    __shared__ float red[4];
    int lane = threadIdx.x & 63;
    int wave = threadIdx.x >> 6;
    if (lane == 0) red[wave] = v;
    __syncthreads();
    if (threadIdx.x == 0)
        partials[blk] = (red[0] + red[1]) + (red[2] + red[3]);
}

// ---------------------------------------------------------------------------
// Kernel 3: finalize — sum 4352 weighted partials, / (32*32*32768).
// ---------------------------------------------------------------------------
__global__ __launch_bounds__(256) void fin_kernel(const float* __restrict__ partials,
                                                  float* __restrict__ out) {
    double s = 0.0;
    for (int p = threadIdx.x; p < NBLK; p += 256) s += (double)partials[p];
    __shared__ double sh[256];
    sh[threadIdx.x] = s;
    __syncthreads();
    for (int m = 128; m > 0; m >>= 1) {
        if (threadIdx.x < m) sh[threadIdx.x] += sh[threadIdx.x + m];
        __syncthreads();
    }
    if (threadIdx.x == 0) out[0] = (float)(sh[0] / 33554432.0);
}

extern "C" void kernel_launch(void* const* d_in, const int* in_sizes, int n_in,
                              void* d_out, int out_size, void* d_ws, size_t ws_size,
                              hipStream_t stream) {
    const float* xa = (const float*)d_in[0];
    const float* xb = (const float*)d_in[1];
    float* fa = (float*)d_ws;
    float* fb = fa + (size_t)N_SAMP * D_FEAT;
    float* partials = fb + (size_t)N_SAMP * D_FEAT;
    float* out = (float*)d_out;

    dim3 pg(4096, 2);
    pool_kernel<<<pg, 256, 0, stream>>>(xa, xb, fa, fb);
    mmd_kernel<<<NBLK, 256, 0, stream>>>(fa, fb, partials);
    fin_kernel<<<1, 256, 0, stream>>>(partials, out);
}